// Round 1
// baseline (527.528 us; speedup 1.0000x reference)
//
#include <hip/hip_runtime.h>
#include <math.h>

// Converse2D on gfx950 — spectral restructuring:
//   out(2y+u, 2x+v) plane = ifft136( A_uv[g] * Xhat[g] ), per (n,c,u,v)
//   Xhat = fft136(wrap_pad(x)); A_uv = per-channel multiplier from weight/bias.
// All FFTs are 136 = 8*17 Cooley-Tukey, done in-LDS (one plane per workgroup).

#define MDIM 136
#define MSTR 137            // padded LDS row stride
#define HC 69               // stored Hermitian half columns (0..68)
#define PLANE_HALF (MDIM*HC)   // 9384 complex per plane
#define NPLANES 256         // N*C
#define LDS_FLOATS (2*MDIM*MSTR + 2*MDIM)
#define PI_D 3.14159265358979323846

__device__ __forceinline__ int slotof(int k) { return 17*(k & 7) + (k >> 3); }

// In-place 1D FFT over one axis of the LDS plane. LS = stride between lines,
// PS = stride between positions within a line. Twiddle LUT holds exp(dir*2πi t/136).
template<int LS, int PS>
__device__ void fft_pass(float* __restrict__ re, float* __restrict__ im,
                         const float* __restrict__ lutc, const float* __restrict__ luts,
                         int tid, int nth)
{
    // Stage 1: 8-point DFT with folded twiddle: out[slot 17*k1+n2] =
    //   sum_{n1} x[17*n1+n2] * exp(dir*2πi*k1*(17*n1+n2)/136)
    for (int e = tid; e < MDIM*17; e += nth) {
        int line = e / 17;
        int n2   = e - line*17;
        int lbase = line*LS;
        float xr[8], xi[8];
#pragma unroll
        for (int n1 = 0; n1 < 8; n1++) {
            int pos = 17*n1 + n2;
            xr[n1] = re[lbase + pos*PS];
            xi[n1] = im[lbase + pos*PS];
        }
        float yr[8], yi[8];
#pragma unroll
        for (int k1 = 0; k1 < 8; k1++) {
            int idx  = k1*n2;    // < 136
            int step = 17*k1;    // < 136
            float ar = 0.f, ai = 0.f;
#pragma unroll
            for (int n1 = 0; n1 < 8; n1++) {
                float c = lutc[idx], s = luts[idx];
                ar = fmaf(xr[n1], c, fmaf(-xi[n1], s, ar));
                ai = fmaf(xr[n1], s, fmaf( xi[n1], c, ai));
                idx += step; if (idx >= MDIM) idx -= MDIM;
            }
            yr[k1] = ar; yi[k1] = ai;
        }
#pragma unroll
        for (int k1 = 0; k1 < 8; k1++) {
            int pos = 17*k1 + n2;
            re[lbase + pos*PS] = yr[k1];
            im[lbase + pos*PS] = yi[k1];
        }
    }
    __syncthreads();
    // Stage 2: direct 17-point DFT. Freq k = k1 + 8*k2 stored at slot 17*k1+k2.
    for (int e = tid; e < MDIM*8; e += nth) {
        int line = e >> 3;
        int k1   = e & 7;
        int lbase = line*LS;
        float xr[17], xi[17];
#pragma unroll
        for (int n2 = 0; n2 < 17; n2++) {
            int pos = 17*k1 + n2;
            xr[n2] = re[lbase + pos*PS];
            xi[n2] = im[lbase + pos*PS];
        }
        for (int k2 = 0; k2 < 17; k2++) {
            int idx = 0;
            int step = 8*k2;   // < 136
            float ar = 0.f, ai = 0.f;
#pragma unroll
            for (int n2 = 0; n2 < 17; n2++) {
                float c = lutc[idx], s = luts[idx];  // lane-uniform -> LDS broadcast
                ar = fmaf(xr[n2], c, fmaf(-xi[n2], s, ar));
                ai = fmaf(xr[n2], s, fmaf( xi[n2], c, ai));
                idx += step; if (idx >= MDIM) idx -= MDIM;
            }
            int pos = 17*k1 + k2;
            re[lbase + pos*PS] = ar;
            im[lbase + pos*PS] = ai;
        }
    }
    __syncthreads();
}

// Forward: one WG per (n,c) plane. Build wrap-padded xp in LDS, 2D FFT,
// store Hermitian half (columns 0..68), unpermuting slots.
__global__ __launch_bounds__(1024) void fwd_kernel(const float* __restrict__ x,
                                                   float2* __restrict__ Xhat)
{
    extern __shared__ float smem[];
    float* re   = smem;
    float* im   = smem + MDIM*MSTR;
    float* lutc = smem + 2*MDIM*MSTR;
    float* luts = lutc + MDIM;
    const int tid = threadIdx.x, nth = blockDim.x;

    for (int t = tid; t < MDIM; t += nth) {
        double ang = -2.0*PI_D*(double)t/136.0;
        double s, c; sincos(ang, &s, &c);
        lutc[t] = (float)c; luts[t] = (float)s;
    }
    const float* xp = x + (size_t)blockIdx.x * (128*128);
    for (int e = tid; e < MDIM*MDIM; e += nth) {
        int i = e / MDIM, j = e - i*MDIM;
        int si = (i + 124) & 127, sj = (j + 124) & 127;   // wrap pad by 4
        re[i*MSTR + j] = xp[si*128 + sj];
        im[i*MSTR + j] = 0.f;
    }
    __syncthreads();
    fft_pass<MSTR, 1>(re, im, lutc, luts, tid, nth);   // rows
    fft_pass<1, MSTR>(re, im, lutc, luts, tid, nth);   // cols

    float2* outp = Xhat + (size_t)blockIdx.x * PLANE_HALF;
    for (int e = tid; e < PLANE_HALF; e += nth) {
        int g1 = e / HC, g2 = e - g1*HC;
        int a = slotof(g1)*MSTR + slotof(g2);
        outp[e] = make_float2(re[a], im[a]);
    }
}

// Per-channel multiplier precompute (double precision; errors here get
// amplified by up to 1/(invW+r) ~ 7.5e3). Stores A_uv half-planes with the
// 1/(4*136^2) ifft normalization folded in.
__global__ void prep_kernel(const float* __restrict__ weight,
                            const float* __restrict__ bias,
                            float2* __restrict__ Abuf)
{
    const int c = blockIdx.x;
    const float* wp = weight + c*25;
    double w[25];
#pragma unroll
    for (int i = 0; i < 25; i++) w[i] = (double)wp[i];
    const double r = 1.0/(1.0 + exp(9.0 - (double)bias[c])) + 1e-5;

    const double THB = -2.0*PI_D/272.0;
    for (int e = threadIdx.x; e < PLANE_HALF; e += blockDim.x) {
        int g1 = e / HC, g2 = e - g1*HC;
        double s1, c1, s2, c2;
        sincos(THB*(double)g1, &s1, &c1);
        sincos(THB*(double)g2, &s2, &c2);
        // exp(-2πi g t/272) for t=-2..2 (index 0..4)
        double e1r[5], e1i[5], e2r[5], e2i[5];
        e1r[2]=1.0; e1i[2]=0.0; e1r[3]=c1; e1i[3]=s1;
        e1r[4]=c1*c1-s1*s1; e1i[4]=2.0*c1*s1;
        e1r[1]=c1; e1i[1]=-s1; e1r[0]=e1r[4]; e1i[0]=-e1i[4];
        e2r[2]=1.0; e2i[2]=0.0; e2r[3]=c2; e2i[3]=s2;
        e2r[4]=c2*c2-s2*s2; e2i[4]=2.0*c2*s2;
        e2r[1]=c2; e2i[1]=-s2; e2r[0]=e2r[4]; e2i[0]=-e2i[4];

        // Row sums over b for both f2-alias signs ((-1)^b)
        double R0r[5],R0i[5],R1r[5],R1i[5];
#pragma unroll
        for (int a = 0; a < 5; a++) {
            double r0r=0,r0i=0,r1r=0,r1i=0;
#pragma unroll
            for (int b = 0; b < 5; b++) {
                double wv = w[a*5+b];
                double pr = wv*e2r[b], pi = wv*e2i[b];
                r0r += pr; r0i += pi;
                if (b & 1) { r1r -= pr; r1i -= pi; } else { r1r += pr; r1i += pi; }
            }
            R0r[a]=r0r; R0i[a]=r0i; R1r[a]=r1r; R1i[a]=r1i;
        }
        // FB at the 4 aliases (f + {0,136} per axis); f1-alias flips (-1)^a
        double FBr[2][2], FBi[2][2];
#pragma unroll
        for (int a1 = 0; a1 < 2; a1++)
#pragma unroll
            for (int b1 = 0; b1 < 2; b1++) {
                double fr=0, fi=0;
#pragma unroll
                for (int a = 0; a < 5; a++) {
                    double er = e1r[a], ei = e1i[a];
                    if (a1 && (a & 1)) { er = -er; ei = -ei; }
                    double Rr = b1 ? R1r[a] : R0r[a];
                    double Ri = b1 ? R1i[a] : R0i[a];
                    fr += er*Rr - ei*Ri;
                    fi += er*Ri + ei*Rr;
                }
                FBr[a1][b1]=fr; FBi[a1][b1]=fi;
            }
        // B = (1 ± e^{-iθ1})(1 ± e^{-iθ2}) at aliases
        double ur[2]={1.0+c1, 1.0-c1}, ui[2]={s1, -s1};
        double vr[2]={1.0+c2, 1.0-c2}, vi[2]={s2, -s2};
        double Br_[2][2], Bi_[2][2];
#pragma unroll
        for (int a1 = 0; a1 < 2; a1++)
#pragma unroll
            for (int b1 = 0; b1 < 2; b1++) {
                Br_[a1][b1] = ur[a1]*vr[b1] - ui[a1]*vi[b1];
                Bi_[a1][b1] = ur[a1]*vi[b1] + ui[a1]*vr[b1];
            }
        double invW=0, Qr=0, Qi=0;
#pragma unroll
        for (int a1 = 0; a1 < 2; a1++)
#pragma unroll
            for (int b1 = 0; b1 < 2; b1++) {
                invW += FBr[a1][b1]*FBr[a1][b1] + FBi[a1][b1]*FBi[a1][b1];
                Qr += FBr[a1][b1]*Br_[a1][b1] - FBi[a1][b1]*Bi_[a1][b1];
                Qi += FBr[a1][b1]*Bi_[a1][b1] + FBi[a1][b1]*Br_[a1][b1];
            }
        invW *= 0.25; Qr *= 0.25; Qi *= 0.25;
        double den = 1.0/(invW + r);
        double Sr = (1.0 - Qr)*den, Si = -Qi*den;
        // M = B + conj(FB)*S  (the 1/r cancellation is already done analytically)
        double Mr[2][2], Mi[2][2];
#pragma unroll
        for (int a1 = 0; a1 < 2; a1++)
#pragma unroll
            for (int b1 = 0; b1 < 2; b1++) {
                Mr[a1][b1] = Br_[a1][b1] + FBr[a1][b1]*Sr + FBi[a1][b1]*Si;
                Mi[a1][b1] = Bi_[a1][b1] + FBr[a1][b1]*Si - FBi[a1][b1]*Sr;
            }
        const double scale = 1.0/73984.0;   // 1/272^2 ifft normalization
#pragma unroll
        for (int uu = 0; uu < 2; uu++)
#pragma unroll
            for (int vv = 0; vv < 2; vv++) {
                double sr=0, si=0;
#pragma unroll
                for (int a1 = 0; a1 < 2; a1++)
#pragma unroll
                    for (int b1 = 0; b1 < 2; b1++) {
                        if ((a1*uu + b1*vv) & 1) { sr -= Mr[a1][b1]; si -= Mi[a1][b1]; }
                        else                     { sr += Mr[a1][b1]; si += Mi[a1][b1]; }
                    }
                double ang = PI_D*(double)(g1*uu + g2*vv)/136.0;
                double ps, pc; sincos(ang, &ps, &pc);
                float2 outv;
                outv.x = (float)((pc*sr - ps*si)*scale);
                outv.y = (float)((pc*si + ps*sr)*scale);
                Abuf[((size_t)(c*4 + uu*2 + vv))*PLANE_HALF + e] = outv;
            }
    }
}

// Inverse: one WG per (n,c,u,v). Y = A*Xhat expanded from Hermitian half to
// full plane in LDS, 2D ifft, write the cropped parity plane.
__global__ __launch_bounds__(1024) void inv_kernel(const float2* __restrict__ Xhat,
                                                   const float2* __restrict__ Abuf,
                                                   float* __restrict__ out)
{
    extern __shared__ float smem[];
    float* re   = smem;
    float* im   = smem + MDIM*MSTR;
    float* lutc = smem + 2*MDIM*MSTR;
    float* luts = lutc + MDIM;
    const int tid = threadIdx.x, nth = blockDim.x;

    for (int t = tid; t < MDIM; t += nth) {
        double ang = 2.0*PI_D*(double)t/136.0;    // inverse direction
        double s, c; sincos(ang, &s, &c);
        lutc[t] = (float)c; luts[t] = (float)s;
    }
    const int p  = blockIdx.x;
    const int v  = p & 1;
    const int u  = (p >> 1) & 1;
    const int nc = p >> 2;            // n*64 + c
    const int c  = nc & 63;
    const float2* Xp = Xhat + (size_t)nc * PLANE_HALF;
    const float2* Ap = Abuf + (size_t)(c*4 + u*2 + v) * PLANE_HALF;

    for (int e = tid; e < PLANE_HALF; e += nth) {
        int g1 = e / HC, g2 = e - g1*HC;
        float2 xv = Xp[e], av = Ap[e];
        float yr = av.x*xv.x - av.y*xv.y;
        float yi = av.x*xv.y + av.y*xv.x;
        re[g1*MSTR + g2] = yr;
        im[g1*MSTR + g2] = yi;
        if (g2 >= 1 && g2 < 68) {     // Hermitian reflection fills cols 69..135
            int rg1 = (g1 == 0) ? 0 : (MDIM - g1);
            int rg2 = MDIM - g2;
            re[rg1*MSTR + rg2] = yr;
            im[rg1*MSTR + rg2] = -yi;
        }
    }
    __syncthreads();
    fft_pass<MSTR, 1>(re, im, lutc, luts, tid, nth);
    fft_pass<1, MSTR>(re, im, lutc, luts, tid, nth);

    float* op = out + (size_t)nc * (256*256);
    for (int e = tid; e < 128*128; e += nth) {
        int y1 = (e >> 7) + 4, y2 = (e & 127) + 4;   // keep y in [4,132)
        int o1 = 2*y1 + u - 8, o2 = 2*y2 + v - 8;
        op[o1*256 + o2] = re[slotof(y1)*MSTR + slotof(y2)];
    }
}

extern "C" void kernel_launch(void* const* d_in, const int* in_sizes, int n_in,
                              void* d_out, int out_size, void* d_ws, size_t ws_size,
                              hipStream_t stream)
{
    const float* x      = (const float*)d_in[0];
    const float* weight = (const float*)d_in[1];
    const float* bias   = (const float*)d_in[2];
    float* out = (float*)d_out;

    float2* Xhat = (float2*)d_ws;                       // 256 * 9384 * 8B = 19.2 MB
    float2* Abuf = Xhat + (size_t)NPLANES * PLANE_HALF; // 256 * 9384 * 8B = 19.2 MB

    const size_t lds_bytes = (size_t)LDS_FLOATS * sizeof(float);  // 150,144 B
    (void)hipFuncSetAttribute((const void*)fwd_kernel,
                              hipFuncAttributeMaxDynamicSharedMemorySize, (int)lds_bytes);
    (void)hipFuncSetAttribute((const void*)inv_kernel,
                              hipFuncAttributeMaxDynamicSharedMemorySize, (int)lds_bytes);

    prep_kernel<<<64, 256, 0, stream>>>(weight, bias, Abuf);
    fwd_kernel<<<NPLANES, 1024, lds_bytes, stream>>>(x, Xhat);
    inv_kernel<<<NPLANES*4, 1024, lds_bytes, stream>>>(Xhat, Abuf, out);
}

// Round 2
// 275.206 us; speedup vs baseline: 1.9168x; 1.9168x over previous
//
#include <hip/hip_runtime.h>
#include <math.h>

// Converse2D on gfx950 — spectral restructuring:
//   out(2y+u, 2x+v) plane = ifft136( A_uv[g] * Xhat[g] ), per (n,c,u,v)
//   Xhat = fft136(wrap_pad(x)); A_uv = per-channel multiplier from weight/bias.
// All FFTs are 136 = 8*17 Cooley-Tukey, in-LDS, one plane per workgroup.
// R1: real-FFT packing (2 planes / complex FFT fwd, 2 parities / ifft inv),
//     register radix-8 stage 1 (kills the LUT bank conflicts), prep over 512 blocks.

#define MDIM 136
#define MSTR 137            // padded LDS row stride
#define HC 69               // stored Hermitian half columns (0..68)
#define PLANE_HALF (MDIM*HC)   // 9384 complex per plane
#define NPLANES 256         // N*C
#define LDS_FLOATS (2*MDIM*MSTR + 2*MDIM)
#define PI_D 3.14159265358979323846

__device__ __forceinline__ int slotof(int k) { return 17*(k & 7) + (k >> 3); }

// In-place 1D FFT over one axis of the LDS plane. LS = stride between lines,
// PS = stride between positions within a line. DIR must match the LUT
// (lut[t] = exp(DIR*2*pi*i*t/136)).
template<int LS, int PS, int DIR>
__device__ void fft_pass(float* __restrict__ re, float* __restrict__ im,
                         const float* __restrict__ lutc, const float* __restrict__ luts,
                         int tid, int nth)
{
    constexpr float d = (DIR > 0) ? 1.0f : -1.0f;
    constexpr float C707 = 0.70710678118654752f;
    // Stage 1: radix-8 butterfly (register twiddles) + folded twiddle w^k1,
    // w = lut[n2]. out[slot 17*k1+n2] = w^k1 * DFT8_k1(x[17*n1+n2]).
    for (int e = tid; e < MDIM*17; e += nth) {
        int line = e / 17;
        int n2   = e - line*17;
        int lbase = line*LS;
        float xr[8], xi[8];
#pragma unroll
        for (int n1 = 0; n1 < 8; n1++) {
            int pos = 17*n1 + n2;
            xr[n1] = re[lbase + pos*PS];
            xi[n1] = im[lbase + pos*PS];
        }
        // DFT-4 on evens (x0,x2,x4,x6)
        float e0r = xr[0]+xr[4], e0i = xi[0]+xi[4];
        float e1r = xr[0]-xr[4], e1i = xi[0]-xi[4];
        float o0r = xr[2]+xr[6], o0i = xi[2]+xi[6];
        float o1r = xr[2]-xr[6], o1i = xi[2]-xi[6];
        float E0r = e0r+o0r, E0i = e0i+o0i;
        float E2r = e0r-o0r, E2i = e0i-o0i;
        float E1r = e1r - d*o1i, E1i = e1i + d*o1r;
        float E3r = e1r + d*o1i, E3i = e1i - d*o1r;
        // DFT-4 on odds (x1,x3,x5,x7)
        float f0r = xr[1]+xr[5], f0i = xi[1]+xi[5];
        float f1r = xr[1]-xr[5], f1i = xi[1]-xi[5];
        float h0r = xr[3]+xr[7], h0i = xi[3]+xi[7];
        float h1r = xr[3]-xr[7], h1i = xi[3]-xi[7];
        float O0r = f0r+h0r, O0i = f0i+h0i;
        float O2r = f0r-h0r, O2i = f0i-h0i;
        float O1r = f1r - d*h1i, O1i = f1i + d*h1r;
        float O3r = f1r + d*h1i, O3i = f1i - d*h1r;
        // combine with w8^k twiddles
        float t1r =  C707*(O1r - d*O1i), t1i = C707*(O1i + d*O1r);
        float t2r = -d*O2i,              t2i = d*O2r;
        float t3r = -C707*(O3r + d*O3i), t3i = C707*(d*O3r - O3i);
        float Xr[8], Xi[8];
        Xr[0]=E0r+O0r; Xi[0]=E0i+O0i;  Xr[4]=E0r-O0r; Xi[4]=E0i-O0i;
        Xr[1]=E1r+t1r; Xi[1]=E1i+t1i;  Xr[5]=E1r-t1r; Xi[5]=E1i-t1i;
        Xr[2]=E2r+t2r; Xi[2]=E2i+t2i;  Xr[6]=E2r-t2r; Xi[6]=E2i-t2i;
        Xr[3]=E3r+t3r; Xi[3]=E3i+t3i;  Xr[7]=E3r-t3r; Xi[7]=E3i-t3i;
        // folded twiddle by recurrence: cur = w^k1, w = exp(DIR*2pi*i*n2/136)
        float wr = lutc[n2], wi = luts[n2];
        float cr = 1.f, ci = 0.f;
#pragma unroll
        for (int k1 = 0; k1 < 8; k1++) {
            int pos = 17*k1 + n2;
            re[lbase + pos*PS] = Xr[k1]*cr - Xi[k1]*ci;
            im[lbase + pos*PS] = Xr[k1]*ci + Xi[k1]*cr;
            float ncr = cr*wr - ci*wi;
            ci = cr*wi + ci*wr; cr = ncr;
        }
    }
    __syncthreads();
    // Stage 2: direct 17-point DFT. Freq k = k1 + 8*k2 stored at slot 17*k1+k2.
    for (int e = tid; e < MDIM*8; e += nth) {
        int line = e >> 3;
        int k1   = e & 7;
        int lbase = line*LS;
        float xr[17], xi[17];
#pragma unroll
        for (int n2 = 0; n2 < 17; n2++) {
            int pos = 17*k1 + n2;
            xr[n2] = re[lbase + pos*PS];
            xi[n2] = im[lbase + pos*PS];
        }
        for (int k2 = 0; k2 < 17; k2++) {
            int idx = 0;
            int step = 8*k2;   // < 136
            float ar = 0.f, ai = 0.f;
#pragma unroll
            for (int n2 = 0; n2 < 17; n2++) {
                float c = lutc[idx], s = luts[idx];  // lane-uniform -> LDS broadcast
                ar = fmaf(xr[n2], c, fmaf(-xi[n2], s, ar));
                ai = fmaf(xr[n2], s, fmaf( xi[n2], c, ai));
                idx += step; if (idx >= MDIM) idx -= MDIM;
            }
            int pos = 17*k1 + k2;
            re[lbase + pos*PS] = ar;
            im[lbase + pos*PS] = ai;
        }
    }
    __syncthreads();
}

// Forward: one WG per plane PAIR (2p, 2p+1). Z = x[2p] + i*x[2p+1] (wrap-padded),
// 2D FFT, Hermitian split, store both half-planes.
__global__ __launch_bounds__(1024) void fwd_kernel(const float* __restrict__ x,
                                                   float2* __restrict__ Xhat)
{
    extern __shared__ float smem[];
    float* re   = smem;
    float* im   = smem + MDIM*MSTR;
    float* lutc = smem + 2*MDIM*MSTR;
    float* luts = lutc + MDIM;
    const int tid = threadIdx.x, nth = blockDim.x;

    for (int t = tid; t < MDIM; t += nth) {
        double ang = -2.0*PI_D*(double)t/136.0;
        double s, c; sincos(ang, &s, &c);
        lutc[t] = (float)c; luts[t] = (float)s;
    }
    const float* xa = x + (size_t)(2*blockIdx.x)     * (128*128);
    const float* xb = x + (size_t)(2*blockIdx.x + 1) * (128*128);
    for (int e = tid; e < MDIM*MDIM; e += nth) {
        int i = e / MDIM, j = e - i*MDIM;
        int si = (i + 124) & 127, sj = (j + 124) & 127;   // wrap pad by 4
        re[i*MSTR + j] = xa[si*128 + sj];
        im[i*MSTR + j] = xb[si*128 + sj];
    }
    __syncthreads();
    fft_pass<MSTR, 1, -1>(re, im, lutc, luts, tid, nth);   // rows
    fft_pass<1, MSTR, -1>(re, im, lutc, luts, tid, nth);   // cols

    float2* outA = Xhat + (size_t)(2*blockIdx.x)     * PLANE_HALF;
    float2* outB = Xhat + (size_t)(2*blockIdx.x + 1) * PLANE_HALF;
    for (int e = tid; e < PLANE_HALF; e += nth) {
        int g1 = e / HC, g2 = e - g1*HC;
        int ng1 = (g1 == 0) ? 0 : MDIM - g1;
        int ng2 = (g2 == 0) ? 0 : MDIM - g2;
        int a = slotof(g1)*MSTR + slotof(g2);
        int b = slotof(ng1)*MSTR + slotof(ng2);
        float Zr = re[a], Zi = im[a];
        float Wr = re[b], Wi = im[b];
        // A = (Z(g)+conj(Z(-g)))/2 ; B = -i/2 * (Z(g)-conj(Z(-g)))
        outA[e] = make_float2(0.5f*(Zr + Wr), 0.5f*(Zi - Wi));
        outB[e] = make_float2(0.5f*(Zi + Wi), 0.5f*(Wr - Zr));
    }
}

// Per-channel multiplier precompute (double precision; errors here get
// amplified by up to 1/(invW+r) ~ 7.5e3). Stores A_uv half-planes with the
// 1/(4*136^2) ifft normalization folded in. 8 blocks per channel.
__global__ void prep_kernel(const float* __restrict__ weight,
                            const float* __restrict__ bias,
                            float2* __restrict__ Abuf)
{
    const int c     = blockIdx.x >> 3;
    const int chunk = blockIdx.x & 7;
    const float* wp = weight + c*25;
    double w[25];
#pragma unroll
    for (int i = 0; i < 25; i++) w[i] = (double)wp[i];
    const double r = 1.0/(1.0 + exp(9.0 - (double)bias[c])) + 1e-5;

    const double THB = -2.0*PI_D/272.0;
    const int e_lo = chunk * 1173;           // 8*1173 == PLANE_HALF
    const int e_hi = e_lo + 1173;
    for (int e = e_lo + threadIdx.x; e < e_hi; e += blockDim.x) {
        int g1 = e / HC, g2 = e - g1*HC;
        double s1, c1, s2, c2;
        sincos(THB*(double)g1, &s1, &c1);
        sincos(THB*(double)g2, &s2, &c2);
        double e1r[5], e1i[5], e2r[5], e2i[5];
        e1r[2]=1.0; e1i[2]=0.0; e1r[3]=c1; e1i[3]=s1;
        e1r[4]=c1*c1-s1*s1; e1i[4]=2.0*c1*s1;
        e1r[1]=c1; e1i[1]=-s1; e1r[0]=e1r[4]; e1i[0]=-e1i[4];
        e2r[2]=1.0; e2i[2]=0.0; e2r[3]=c2; e2i[3]=s2;
        e2r[4]=c2*c2-s2*s2; e2i[4]=2.0*c2*s2;
        e2r[1]=c2; e2i[1]=-s2; e2r[0]=e2r[4]; e2i[0]=-e2i[4];

        double R0r[5],R0i[5],R1r[5],R1i[5];
#pragma unroll
        for (int a = 0; a < 5; a++) {
            double r0r=0,r0i=0,r1r=0,r1i=0;
#pragma unroll
            for (int b = 0; b < 5; b++) {
                double wv = w[a*5+b];
                double pr = wv*e2r[b], pi = wv*e2i[b];
                r0r += pr; r0i += pi;
                if (b & 1) { r1r -= pr; r1i -= pi; } else { r1r += pr; r1i += pi; }
            }
            R0r[a]=r0r; R0i[a]=r0i; R1r[a]=r1r; R1i[a]=r1i;
        }
        double FBr[2][2], FBi[2][2];
#pragma unroll
        for (int a1 = 0; a1 < 2; a1++)
#pragma unroll
            for (int b1 = 0; b1 < 2; b1++) {
                double fr=0, fi=0;
#pragma unroll
                for (int a = 0; a < 5; a++) {
                    double er = e1r[a], ei = e1i[a];
                    if (a1 && (a & 1)) { er = -er; ei = -ei; }
                    double Rr = b1 ? R1r[a] : R0r[a];
                    double Ri = b1 ? R1i[a] : R0i[a];
                    fr += er*Rr - ei*Ri;
                    fi += er*Ri + ei*Rr;
                }
                FBr[a1][b1]=fr; FBi[a1][b1]=fi;
            }
        double ur[2]={1.0+c1, 1.0-c1}, ui[2]={s1, -s1};
        double vr[2]={1.0+c2, 1.0-c2}, vi[2]={s2, -s2};
        double Br_[2][2], Bi_[2][2];
#pragma unroll
        for (int a1 = 0; a1 < 2; a1++)
#pragma unroll
            for (int b1 = 0; b1 < 2; b1++) {
                Br_[a1][b1] = ur[a1]*vr[b1] - ui[a1]*vi[b1];
                Bi_[a1][b1] = ur[a1]*vi[b1] + ui[a1]*vr[b1];
            }
        double invW=0, Qr=0, Qi=0;
#pragma unroll
        for (int a1 = 0; a1 < 2; a1++)
#pragma unroll
            for (int b1 = 0; b1 < 2; b1++) {
                invW += FBr[a1][b1]*FBr[a1][b1] + FBi[a1][b1]*FBi[a1][b1];
                Qr += FBr[a1][b1]*Br_[a1][b1] - FBi[a1][b1]*Bi_[a1][b1];
                Qi += FBr[a1][b1]*Bi_[a1][b1] + FBi[a1][b1]*Br_[a1][b1];
            }
        invW *= 0.25; Qr *= 0.25; Qi *= 0.25;
        double den = 1.0/(invW + r);
        double Sr = (1.0 - Qr)*den, Si = -Qi*den;
        double Mr[2][2], Mi[2][2];
#pragma unroll
        for (int a1 = 0; a1 < 2; a1++)
#pragma unroll
            for (int b1 = 0; b1 < 2; b1++) {
                Mr[a1][b1] = Br_[a1][b1] + FBr[a1][b1]*Sr + FBi[a1][b1]*Si;
                Mi[a1][b1] = Bi_[a1][b1] + FBr[a1][b1]*Si - FBi[a1][b1]*Sr;
            }
        const double scale = 1.0/73984.0;   // 1/272^2 ifft normalization
#pragma unroll
        for (int uu = 0; uu < 2; uu++)
#pragma unroll
            for (int vv = 0; vv < 2; vv++) {
                double sr=0, si=0;
#pragma unroll
                for (int a1 = 0; a1 < 2; a1++)
#pragma unroll
                    for (int b1 = 0; b1 < 2; b1++) {
                        if ((a1*uu + b1*vv) & 1) { sr -= Mr[a1][b1]; si -= Mi[a1][b1]; }
                        else                     { sr += Mr[a1][b1]; si += Mi[a1][b1]; }
                    }
                double ang = PI_D*(double)(g1*uu + g2*vv)/136.0;
                double ps, pc; sincos(ang, &ps, &pc);
                float2 outv;
                outv.x = (float)((pc*sr - ps*si)*scale);
                outv.y = (float)((pc*si + ps*sr)*scale);
                Abuf[((size_t)(c*4 + uu*2 + vv))*PLANE_HALF + e] = outv;
            }
    }
}

// Inverse: one WG per (n,c,u). Y = (A_u0 + i*A_u1)*Xhat expanded to the full
// plane in LDS (modified-Hermitian reflection), 2D ifft; Re -> v=0 columns,
// Im -> v=1 columns, written as one coalesced float2 per (row, col-pair).
__global__ __launch_bounds__(1024) void inv_kernel(const float2* __restrict__ Xhat,
                                                   const float2* __restrict__ Abuf,
                                                   float* __restrict__ out)
{
    extern __shared__ float smem[];
    float* re   = smem;
    float* im   = smem + MDIM*MSTR;
    float* lutc = smem + 2*MDIM*MSTR;
    float* luts = lutc + MDIM;
    const int tid = threadIdx.x, nth = blockDim.x;

    for (int t = tid; t < MDIM; t += nth) {
        double ang = 2.0*PI_D*(double)t/136.0;    // inverse direction
        double s, c; sincos(ang, &s, &c);
        lutc[t] = (float)c; luts[t] = (float)s;
    }
    const int p  = blockIdx.x;        // 0..511
    const int u  = p & 1;
    const int nc = p >> 1;            // n*64 + c
    const int c  = nc & 63;
    const float2* Xp = Xhat + (size_t)nc * PLANE_HALF;
    const float2* A0 = Abuf + (size_t)(c*4 + u*2 + 0) * PLANE_HALF;
    const float2* A1 = Abuf + (size_t)(c*4 + u*2 + 1) * PLANE_HALF;

    for (int e = tid; e < PLANE_HALF; e += nth) {
        int g1 = e / HC, g2 = e - g1*HC;
        float2 xv = Xp[e], a0 = A0[e], a1 = A1[e];
        float y0r = a0.x*xv.x - a0.y*xv.y;
        float y0i = a0.x*xv.y + a0.y*xv.x;
        float y1r = a1.x*xv.x - a1.y*xv.y;
        float y1i = a1.x*xv.y + a1.y*xv.x;
        // plane(g) = y0 + i*y1
        re[g1*MSTR + g2] = y0r - y1i;
        im[g1*MSTR + g2] = y0i + y1r;
        if (g2 >= 1 && g2 < 68) {     // fill cols 69..135: plane(-g) = conj(y0)+i*conj(y1)
            int rg1 = (g1 == 0) ? 0 : (MDIM - g1);
            int rg2 = MDIM - g2;
            re[rg1*MSTR + rg2] = y0r + y1i;
            im[rg1*MSTR + rg2] = y1r - y0i;
        }
    }
    __syncthreads();
    fft_pass<MSTR, 1, 1>(re, im, lutc, luts, tid, nth);
    fft_pass<1, MSTR, 1>(re, im, lutc, luts, tid, nth);

    float* op = out + (size_t)nc * (256*256);
    for (int e = tid; e < 128*128; e += nth) {
        int y1 = (e >> 7) + 4, y2 = (e & 127) + 4;   // y in [4,132)
        int o1 = 2*y1 + u - 8;
        int a  = slotof(y1)*MSTR + slotof(y2);
        float2 v2 = make_float2(re[a], im[a]);        // (v=0, v=1)
        *reinterpret_cast<float2*>(op + o1*256 + 2*(y2 - 4)) = v2;
    }
}

extern "C" void kernel_launch(void* const* d_in, const int* in_sizes, int n_in,
                              void* d_out, int out_size, void* d_ws, size_t ws_size,
                              hipStream_t stream)
{
    const float* x      = (const float*)d_in[0];
    const float* weight = (const float*)d_in[1];
    const float* bias   = (const float*)d_in[2];
    float* out = (float*)d_out;

    float2* Xhat = (float2*)d_ws;                       // 256 * 9384 * 8B = 19.2 MB
    float2* Abuf = Xhat + (size_t)NPLANES * PLANE_HALF; // 256 * 9384 * 8B = 19.2 MB

    const size_t lds_bytes = (size_t)LDS_FLOATS * sizeof(float);  // 150,144 B
    (void)hipFuncSetAttribute((const void*)fwd_kernel,
                              hipFuncAttributeMaxDynamicSharedMemorySize, (int)lds_bytes);
    (void)hipFuncSetAttribute((const void*)inv_kernel,
                              hipFuncAttributeMaxDynamicSharedMemorySize, (int)lds_bytes);

    prep_kernel<<<512, 256, 0, stream>>>(weight, bias, Abuf);
    fwd_kernel<<<NPLANES/2, 1024, lds_bytes, stream>>>(x, Xhat);
    inv_kernel<<<NPLANES*2, 1024, lds_bytes, stream>>>(Xhat, Abuf, out);
}

// Round 3
// 251.068 us; speedup vs baseline: 2.1011x; 1.0961x over previous
//
#include <hip/hip_runtime.h>
#include <math.h>

// Converse2D on gfx950 — spectral restructuring (R2):
//   out(2y+u, 2x+v) plane = ifft136( A_uv[g] * Xhat[g] ), per (n,c,u,v)
//   Xhat = rfft136x136(wrap_pad(x)); A_uv = per-channel multiplier (Hermitian).
// R2: half-spectrum everywhere -> LDS 77 KB -> 2 blocks/CU (32 waves).
//   fwd: rows = 68-pt CT on packed even/odd cols + r2c unpack (69 cols), col pass 69x fft136.
//   inv: per (u,v): col pass on 69 stored cols, rows = Hermitian c2r via 68-pt CT.
//   prep: table-driven trig (272-entry LDS table), double math.

#define MDIM 136
#define RS   70             // padded LDS row stride (69 stored cols + 1)
#define HC   69             // stored Hermitian half columns (0..68)
#define PLANE_HALF (MDIM*HC)   // 9384 complex per plane
#define NPLANES 256         // N*C
#define LDS_FLOATS (2*MDIM*RS + 2*MDIM)   // re+im planes + cos/sin LUT
#define PI_D 3.14159265358979323846

__device__ __forceinline__ int slot136(int k) { return 17*(k & 7) + (k >> 3); }
__device__ __forceinline__ int slot68(int k)  { return 17*(k & 3) + (k >> 2); }

// ---------- 136-point CT (8x17) along COLUMNS (positions stride RS) ----------
// Transforms `ncols` independent columns c: X[k1+8k2] lands at row-slot 17k1+k2.
// lut[t] = exp(DIR*2*pi*i*t/136).
template<int DIR>
__device__ void fft136_cols(float* __restrict__ re, float* __restrict__ im,
                            const float* __restrict__ lutc, const float* __restrict__ luts,
                            int ncols, int tid, int nth)
{
    constexpr float d = (DIR > 0) ? 1.0f : -1.0f;
    constexpr float C707 = 0.70710678118654752f;
    // Stage 1: radix-8 butterfly + folded twiddle w^k1, w = lut[n2].
    for (int e = tid; e < ncols*17; e += nth) {
        int c  = e / 17;
        int n2 = e - c*17;
        float xr[8], xi[8];
#pragma unroll
        for (int n1 = 0; n1 < 8; n1++) {
            int a = (17*n1 + n2)*RS + c;
            xr[n1] = re[a]; xi[n1] = im[a];
        }
        float e0r = xr[0]+xr[4], e0i = xi[0]+xi[4];
        float e1r = xr[0]-xr[4], e1i = xi[0]-xi[4];
        float o0r = xr[2]+xr[6], o0i = xi[2]+xi[6];
        float o1r = xr[2]-xr[6], o1i = xi[2]-xi[6];
        float E0r = e0r+o0r, E0i = e0i+o0i;
        float E2r = e0r-o0r, E2i = e0i-o0i;
        float E1r = e1r - d*o1i, E1i = e1i + d*o1r;
        float E3r = e1r + d*o1i, E3i = e1i - d*o1r;
        float f0r = xr[1]+xr[5], f0i = xi[1]+xi[5];
        float f1r = xr[1]-xr[5], f1i = xi[1]-xi[5];
        float h0r = xr[3]+xr[7], h0i = xi[3]+xi[7];
        float h1r = xr[3]-xr[7], h1i = xi[3]-xi[7];
        float O0r = f0r+h0r, O0i = f0i+h0i;
        float O2r = f0r-h0r, O2i = f0i-h0i;
        float O1r = f1r - d*h1i, O1i = f1i + d*h1r;
        float O3r = f1r + d*h1i, O3i = f1i - d*h1r;
        float t1r =  C707*(O1r - d*O1i), t1i = C707*(O1i + d*O1r);
        float t2r = -d*O2i,              t2i = d*O2r;
        float t3r = -C707*(O3r + d*O3i), t3i = C707*(d*O3r - O3i);
        float Xr[8], Xi[8];
        Xr[0]=E0r+O0r; Xi[0]=E0i+O0i;  Xr[4]=E0r-O0r; Xi[4]=E0i-O0i;
        Xr[1]=E1r+t1r; Xi[1]=E1i+t1i;  Xr[5]=E1r-t1r; Xi[5]=E1i-t1i;
        Xr[2]=E2r+t2r; Xi[2]=E2i+t2i;  Xr[6]=E2r-t2r; Xi[6]=E2i-t2i;
        Xr[3]=E3r+t3r; Xi[3]=E3i+t3i;  Xr[7]=E3r-t3r; Xi[7]=E3i-t3i;
        float wr = lutc[n2], wi = luts[n2];
        float cr = 1.f, ci = 0.f;
#pragma unroll
        for (int k1 = 0; k1 < 8; k1++) {
            int a = (17*k1 + n2)*RS + c;
            re[a] = Xr[k1]*cr - Xi[k1]*ci;
            im[a] = Xr[k1]*ci + Xi[k1]*cr;
            float ncr = cr*wr - ci*wi;
            ci = cr*wi + ci*wr; cr = ncr;
        }
    }
    __syncthreads();
    // Stage 2: direct 17-point DFT; freq k1+8k2 at slot 17k1+k2.
    for (int e = tid; e < ncols*8; e += nth) {
        int c  = e >> 3;
        int k1 = e & 7;
        float xr[17], xi[17];
#pragma unroll
        for (int n2 = 0; n2 < 17; n2++) {
            int a = (17*k1 + n2)*RS + c;
            xr[n2] = re[a]; xi[n2] = im[a];
        }
        for (int k2 = 0; k2 < 17; k2++) {
            int idx = 0, step = 8*k2;
            float ar = 0.f, ai = 0.f;
#pragma unroll
            for (int n2 = 0; n2 < 17; n2++) {
                float cc = lutc[idx], ss = luts[idx];
                ar = fmaf(xr[n2], cc, fmaf(-xi[n2], ss, ar));
                ai = fmaf(xr[n2], ss, fmaf( xi[n2], cc, ai));
                idx += step; if (idx >= MDIM) idx -= MDIM;
            }
            int a = (17*k1 + k2)*RS + c;
            re[a] = ar; im[a] = ai;
        }
    }
    __syncthreads();
}

// ---------- 68-point CT (4x17) along ROWS (positions stride 1) ----------
// All 136 rows; input natural cols 0..67, output X[k1+4k2] at col-slot 17k1+k2.
// w68 = lut[2], w17 = lut[8] (lut is the 136-periodic table).
template<int DIR>
__device__ void ct68_rows(float* __restrict__ re, float* __restrict__ im,
                          const float* __restrict__ lutc, const float* __restrict__ luts,
                          int tid, int nth)
{
    constexpr float d = (DIR > 0) ? 1.0f : -1.0f;
    // Stage 1: radix-4 + folded twiddle w68^(k1*n2) = lut[2*n2]^k1.
    for (int e = tid; e < MDIM*17; e += nth) {
        int row = e / 17;
        int n2  = e - row*17;
        int base = row*RS;
        float xr[4], xi[4];
#pragma unroll
        for (int n1 = 0; n1 < 4; n1++) {
            xr[n1] = re[base + 17*n1 + n2];
            xi[n1] = im[base + 17*n1 + n2];
        }
        float t0r = xr[0]+xr[2], t0i = xi[0]+xi[2];
        float t1r = xr[0]-xr[2], t1i = xi[0]-xi[2];
        float t2r = xr[1]+xr[3], t2i = xi[1]+xi[3];
        float t3r = xr[1]-xr[3], t3i = xi[1]-xi[3];
        float Xr[4], Xi[4];
        Xr[0] = t0r+t2r;      Xi[0] = t0i+t2i;
        Xr[2] = t0r-t2r;      Xi[2] = t0i-t2i;
        Xr[1] = t1r - d*t3i;  Xi[1] = t1i + d*t3r;
        Xr[3] = t1r + d*t3i;  Xi[3] = t1i - d*t3r;
        float wr = lutc[2*n2], wi = luts[2*n2];
        float cr = 1.f, ci = 0.f;
#pragma unroll
        for (int k1 = 0; k1 < 4; k1++) {
            int a = base + 17*k1 + n2;
            re[a] = Xr[k1]*cr - Xi[k1]*ci;
            im[a] = Xr[k1]*ci + Xi[k1]*cr;
            float ncr = cr*wr - ci*wi;
            ci = cr*wi + ci*wr; cr = ncr;
        }
    }
    __syncthreads();
    // Stage 2: direct 17-point DFT per (row, k1): w17^(n2*k2) = lut[8*n2*k2 mod 136].
    for (int e = tid; e < MDIM*4; e += nth) {
        int row = e >> 2;
        int k1  = e & 3;
        int base = row*RS + 17*k1;
        float xr[17], xi[17];
#pragma unroll
        for (int n2 = 0; n2 < 17; n2++) {
            xr[n2] = re[base + n2];
            xi[n2] = im[base + n2];
        }
        for (int k2 = 0; k2 < 17; k2++) {
            int idx = 0, step = 8*k2;
            float ar = 0.f, ai = 0.f;
#pragma unroll
            for (int n2 = 0; n2 < 17; n2++) {
                float cc = lutc[idx], ss = luts[idx];
                ar = fmaf(xr[n2], cc, fmaf(-xi[n2], ss, ar));
                ai = fmaf(xr[n2], ss, fmaf( xi[n2], cc, ai));
                idx += step; if (idx >= MDIM) idx -= MDIM;
            }
            re[base + k2] = ar;
            im[base + k2] = ai;
        }
    }
    __syncthreads();
}

// ---------- Forward: one WG per (n,c) plane (256 WGs), r2c half-spectrum ----------
__global__ __launch_bounds__(1024, 8) void fwd_kernel(const float* __restrict__ x,
                                                      float2* __restrict__ Xhat)
{
    extern __shared__ float smem[];
    float* re   = smem;
    float* im   = smem + MDIM*RS;
    float* lutc = smem + 2*MDIM*RS;
    float* luts = lutc + MDIM;
    const int tid = threadIdx.x, nth = blockDim.x;

    for (int t = tid; t < MDIM; t += nth) {
        double s, c; sincos(-2.0*PI_D*(double)t/136.0, &s, &c);
        lutc[t] = (float)c; luts[t] = (float)s;
    }
    const float* xp = x + (size_t)blockIdx.x * (128*128);
    // Load packed rows: z[i][n] = xp(i, 2n) + i*xp(i, 2n+1), wrap pad by 4.
    for (int e = tid; e < MDIM*68; e += nth) {
        int i = e / 68, n = e - i*68;
        int si = (i + 124) & 127;
        int j0 = (2*n + 124) & 127;                  // always even, pair never wraps
        const float2 v = *reinterpret_cast<const float2*>(xp + si*128 + j0);
        re[i*RS + n] = v.x;
        im[i*RS + n] = v.y;
    }
    __syncthreads();
    ct68_rows<-1>(re, im, lutc, luts, tid, nth);     // rows: Z[k] at col-slot68(k)
    // r2c unpack: X[k] = E + w136^k * O ; item k handles (k, 68-k), in-place at slots.
    for (int e = tid; e < MDIM*35; e += nth) {
        int row = e / 35, k = e - row*35;
        int base = row*RS;
        int sa = slot68(k);
        float Zar = re[base+sa], Zai = im[base+sa];
        float Zbr, Zbi; int sb;
        if (k == 0) { Zbr = Zar; Zbi = Zai; sb = 68; }  // Z[68] == Z[0]; X[68] -> col 68
        else { int kk = 68-k; sb = slot68(kk); Zbr = re[base+sb]; Zbi = im[base+sb]; }
        float wc = lutc[k], ws = luts[k];               // w136^k (DIR=-1 LUT)
        float Er = 0.5f*(Zar + Zbr), Ei = 0.5f*(Zai - Zbi);
        float Dr = 0.5f*(Zar - Zbr), Di = 0.5f*(Zai + Zbi);
        float Tr = wc*Dr - ws*Di, Ti = wc*Di + ws*Dr;   // w^k * D
        re[base+sa] = Er + Ti;  im[base+sa] = Ei - Tr;  // X[k] = E - i*(w^k D)
        float E2r = Er,  E2i = -Ei;                     // 0.5(Zb + conj Za)
        float D2r = -Dr, D2i = Di;                      // 0.5(Zb - conj Za)
        float w2c = -wc, w2s = ws;                      // w136^(68-k) = -conj(w^k)
        float T2r = w2c*D2r - w2s*D2i, T2i = w2c*D2i + w2s*D2r;
        re[base+sb] = E2r + T2i;  im[base+sb] = E2i - T2r;  // X[68-k]
    }
    __syncthreads();
    fft136_cols<-1>(re, im, lutc, luts, HC, tid, nth);  // 69 columns
    // Store Xhat[g1][g2]; column of g2: slot68(g2) (g2<68) or 68; row: slot136(g1).
    float2* outp = Xhat + (size_t)blockIdx.x * PLANE_HALF;
    for (int e = tid; e < PLANE_HALF; e += nth) {
        int g1 = e / HC, g2 = e - g1*HC;
        int cq = (g2 == 68) ? 68 : slot68(g2);
        int a = slot136(g1)*RS + cq;
        outp[e] = make_float2(re[a], im[a]);
    }
}

// ---------- Per-channel multiplier precompute (double, table-driven trig) ----------
__global__ void prep_kernel(const float* __restrict__ weight,
                            const float* __restrict__ bias,
                            float2* __restrict__ Abuf)
{
    __shared__ double tabc[272], tabs[272];   // exp(-2*pi*i*t/272)
    for (int t = threadIdx.x; t < 272; t += blockDim.x) {
        double s, c; sincos(-2.0*PI_D*(double)t/272.0, &s, &c);
        tabc[t] = c; tabs[t] = s;
    }
    __syncthreads();

    const int c     = blockIdx.x >> 3;
    const int chunk = blockIdx.x & 7;
    const float* wp = weight + c*25;
    double w[25];
#pragma unroll
    for (int i = 0; i < 25; i++) w[i] = (double)wp[i];
    const double r = 1.0/(1.0 + exp(9.0 - (double)bias[c])) + 1e-5;

    const int e_lo = chunk * 1173;           // 8*1173 == PLANE_HALF
    const int e_hi = e_lo + 1173;
    for (int e = e_lo + (int)threadIdx.x; e < e_hi; e += blockDim.x) {
        int g1 = e / HC, g2 = e - g1*HC;
        double c1 = tabc[g1], s1 = tabs[g1];
        double c2 = tabc[g2], s2 = tabs[g2];
        double e1r[5], e1i[5], e2r[5], e2i[5];
        e1r[2]=1.0; e1i[2]=0.0; e1r[3]=c1; e1i[3]=s1;
        e1r[4]=c1*c1-s1*s1; e1i[4]=2.0*c1*s1;
        e1r[1]=c1; e1i[1]=-s1; e1r[0]=e1r[4]; e1i[0]=-e1i[4];
        e2r[2]=1.0; e2i[2]=0.0; e2r[3]=c2; e2i[3]=s2;
        e2r[4]=c2*c2-s2*s2; e2i[4]=2.0*c2*s2;
        e2r[1]=c2; e2i[1]=-s2; e2r[0]=e2r[4]; e2i[0]=-e2i[4];

        double R0r[5],R0i[5],R1r[5],R1i[5];
#pragma unroll
        for (int a = 0; a < 5; a++) {
            double r0r=0,r0i=0,r1r=0,r1i=0;
#pragma unroll
            for (int b = 0; b < 5; b++) {
                double wv = w[a*5+b];
                double pr = wv*e2r[b], pi = wv*e2i[b];
                r0r += pr; r0i += pi;
                if (b & 1) { r1r -= pr; r1i -= pi; } else { r1r += pr; r1i += pi; }
            }
            R0r[a]=r0r; R0i[a]=r0i; R1r[a]=r1r; R1i[a]=r1i;
        }
        double FBr[2][2], FBi[2][2];
#pragma unroll
        for (int a1 = 0; a1 < 2; a1++)
#pragma unroll
            for (int b1 = 0; b1 < 2; b1++) {
                double fr=0, fi=0;
#pragma unroll
                for (int a = 0; a < 5; a++) {
                    double er = e1r[a], ei = e1i[a];
                    if (a1 && (a & 1)) { er = -er; ei = -ei; }
                    double Rr = b1 ? R1r[a] : R0r[a];
                    double Ri = b1 ? R1i[a] : R0i[a];
                    fr += er*Rr - ei*Ri;
                    fi += er*Ri + ei*Rr;
                }
                FBr[a1][b1]=fr; FBi[a1][b1]=fi;
            }
        double ur[2]={1.0+c1, 1.0-c1}, ui[2]={s1, -s1};
        double vr[2]={1.0+c2, 1.0-c2}, vi[2]={s2, -s2};
        double Br_[2][2], Bi_[2][2];
#pragma unroll
        for (int a1 = 0; a1 < 2; a1++)
#pragma unroll
            for (int b1 = 0; b1 < 2; b1++) {
                Br_[a1][b1] = ur[a1]*vr[b1] - ui[a1]*vi[b1];
                Bi_[a1][b1] = ur[a1]*vi[b1] + ui[a1]*vr[b1];
            }
        double invW=0, Qr=0, Qi=0;
#pragma unroll
        for (int a1 = 0; a1 < 2; a1++)
#pragma unroll
            for (int b1 = 0; b1 < 2; b1++) {
                invW += FBr[a1][b1]*FBr[a1][b1] + FBi[a1][b1]*FBi[a1][b1];
                Qr += FBr[a1][b1]*Br_[a1][b1] - FBi[a1][b1]*Bi_[a1][b1];
                Qi += FBr[a1][b1]*Bi_[a1][b1] + FBi[a1][b1]*Br_[a1][b1];
            }
        invW *= 0.25; Qr *= 0.25; Qi *= 0.25;
        double den = 1.0/(invW + r);
        double Sr = (1.0 - Qr)*den, Si = -Qi*den;
        double Mr[2][2], Mi[2][2];
#pragma unroll
        for (int a1 = 0; a1 < 2; a1++)
#pragma unroll
            for (int b1 = 0; b1 < 2; b1++) {
                Mr[a1][b1] = Br_[a1][b1] + FBr[a1][b1]*Sr + FBi[a1][b1]*Si;
                Mi[a1][b1] = Bi_[a1][b1] + FBr[a1][b1]*Si - FBi[a1][b1]*Sr;
            }
        const double scale = 1.0/73984.0;   // 1/272^2 ifft normalization
#pragma unroll
        for (int uu = 0; uu < 2; uu++)
#pragma unroll
            for (int vv = 0; vv < 2; vv++) {
                double sr=0, si=0;
#pragma unroll
                for (int a1 = 0; a1 < 2; a1++)
#pragma unroll
                    for (int b1 = 0; b1 < 2; b1++) {
                        if ((a1*uu + b1*vv) & 1) { sr -= Mr[a1][b1]; si -= Mi[a1][b1]; }
                        else                     { sr += Mr[a1][b1]; si += Mi[a1][b1]; }
                    }
                int t = g1*uu + g2*vv;                 // <= 203 < 272
                double pc = tabc[t], ps = -tabs[t];    // exp(+i*pi*t/136)
                float2 outv;
                outv.x = (float)((pc*sr - ps*si)*scale);
                outv.y = (float)((pc*si + ps*sr)*scale);
                Abuf[((size_t)(c*4 + uu*2 + vv))*PLANE_HALF + e] = outv;
            }
    }
}

// ---------- Inverse: one WG per (n,c,u,v) (1024 WGs), Hermitian half-spectrum ----------
__global__ __launch_bounds__(1024, 8) void inv_kernel(const float2* __restrict__ Xhat,
                                                      const float2* __restrict__ Abuf,
                                                      float* __restrict__ out)
{
    extern __shared__ float smem[];
    float* re   = smem;
    float* im   = smem + MDIM*RS;
    float* lutc = smem + 2*MDIM*RS;
    float* luts = lutc + MDIM;
    const int tid = threadIdx.x, nth = blockDim.x;

    for (int t = tid; t < MDIM; t += nth) {
        double s, c; sincos(2.0*PI_D*(double)t/136.0, &s, &c);   // inverse direction
        lutc[t] = (float)c; luts[t] = (float)s;
    }
    const int p  = blockIdx.x;        // 0..1023
    const int v  = p & 1;
    const int u  = (p >> 1) & 1;
    const int nc = p >> 2;            // n*64 + c
    const int c  = nc & 63;
    const float2* Xp = Xhat + (size_t)nc * PLANE_HALF;
    const float2* Ap = Abuf + (size_t)(c*4 + u*2 + v) * PLANE_HALF;

    // Load S = A_uv * Xhat, natural [g1][g2], g2 = 0..68. (S is Hermitian.)
    for (int e = tid; e < PLANE_HALF; e += nth) {
        int g1 = e / HC, g2 = e - g1*HC;
        float2 xv = Xp[e], av = Ap[e];
        re[g1*RS + g2] = av.x*xv.x - av.y*xv.y;
        im[g1*RS + g2] = av.x*xv.y + av.y*xv.x;
    }
    __syncthreads();
    fft136_cols<1>(re, im, lutc, luts, HC, tid, nth);   // rows become slot136(y1)
    // c2r pack per row: Zf[k] = (T[k]+conj T[68-k]) + i*V^k*(T[k]-conj T[68-k]).
    // Item k in [0,34] handles (k, 68-k): read set == write set -> in-place safe.
    for (int e = tid; e < MDIM*35; e += nth) {
        int row = e / 35, k = e - row*35;
        int base = row*RS;
        float Tar = re[base+k],    Tai = im[base+k];
        float Tbr = re[base+68-k], Tbi = im[base+68-k];
        float Sr = Tar + Tbr, Si = Tai - Tbi;
        float Dr = Tar - Tbr, Di = Tai + Tbi;
        float wc = lutc[k], ws = luts[k];               // V^k = exp(+2pi i k/136)
        float Or = wc*Dr - ws*Di, Oi = wc*Di + ws*Dr;
        re[base+k] = Sr - Oi;                           // Zf[k] = S + i*O
        im[base+k] = Si + Or;
        if (k >= 1 && k <= 33) {                        // Zf[68-k]
            float S2r = Tbr + Tar, S2i = Tbi - Tai;
            float D2r = Tbr - Tar, D2i = Tbi + Tai;
            float w2c = -wc, w2s = ws;                  // V^(68-k) = -conj(V^k)
            float O2r = w2c*D2r - w2s*D2i, O2i = w2c*D2i + w2s*D2r;
            re[base+68-k] = S2r - O2i;
            im[base+68-k] = S2i + O2r;
        }
    }
    __syncthreads();
    ct68_rows<1>(re, im, lutc, luts, tid, nth);         // w[m] at col-slot68(m)
    // Store: row y1 at physical slot136(y1); re -> col 4m+v-8, im -> col 4m+v-6.
    float* op = out + (size_t)nc * (256*256);
    for (int e = tid; e < 128*64; e += nth) {
        int y1 = 4 + (e >> 6);            // [4,132)
        int m  = 2 + (e & 63);            // [2,66)
        int a  = slot136(y1)*RS + slot68(m);
        int o1 = 2*y1 + u - 8;
        float wr = re[a], wi = im[a];
        op[o1*256 + 4*m + v - 8] = wr;    // y2' = 2m   (even within parity grid)
        op[o1*256 + 4*m + v - 6] = wi;    // y2' = 2m+1
    }
}

extern "C" void kernel_launch(void* const* d_in, const int* in_sizes, int n_in,
                              void* d_out, int out_size, void* d_ws, size_t ws_size,
                              hipStream_t stream)
{
    const float* x      = (const float*)d_in[0];
    const float* weight = (const float*)d_in[1];
    const float* bias   = (const float*)d_in[2];
    float* out = (float*)d_out;

    float2* Xhat = (float2*)d_ws;                       // 256 * 9384 * 8B = 19.2 MB
    float2* Abuf = Xhat + (size_t)NPLANES * PLANE_HALF; // 256 * 9384 * 8B = 19.2 MB

    const size_t lds_bytes = (size_t)LDS_FLOATS * sizeof(float);  // 77,248 B
    (void)hipFuncSetAttribute((const void*)fwd_kernel,
                              hipFuncAttributeMaxDynamicSharedMemorySize, (int)lds_bytes);
    (void)hipFuncSetAttribute((const void*)inv_kernel,
                              hipFuncAttributeMaxDynamicSharedMemorySize, (int)lds_bytes);

    prep_kernel<<<512, 256, 0, stream>>>(weight, bias, Abuf);
    fwd_kernel<<<NPLANES, 1024, lds_bytes, stream>>>(x, Xhat);
    inv_kernel<<<NPLANES*4, 1024, lds_bytes, stream>>>(Xhat, Abuf, out);
}

// Round 4
// 156.709 us; speedup vs baseline: 3.3663x; 1.6021x over previous
//
#include <hip/hip_runtime.h>
#include <math.h>

// Converse2D on gfx950 — spectral restructuring (R3):
//   out(2y+u, 2x+v) plane = ifft136( A_uv[g] * Xhat[g] ), per (n,c,u,v)
//   Xhat = rfft136x136(wrap_pad(x)); A_uv = per-channel multiplier (Hermitian).
// R3: symmetric 17-DFT with compile-time (SGPR) twiddles — removes the LDS
//     broadcast-LUT bottleneck in stage 2; XCD swizzle so v-parity pairs share
//     an L2 for write merging.

#define MDIM 136
#define RS   70             // padded LDS row stride (69 stored cols + 1)
#define HC   69             // stored Hermitian half columns (0..68)
#define PLANE_HALF (MDIM*HC)   // 9384 complex per plane
#define NPLANES 256         // N*C
#define LDS_FLOATS (2*MDIM*RS + 2*MDIM)   // re+im planes + cos/sin LUT
#define PI_D 3.14159265358979323846

__device__ __forceinline__ int slot136(int k) { return 17*(k & 7) + (k >> 3); }
__device__ __forceinline__ int slot68(int k)  { return 17*(k & 3) + (k >> 2); }

// ---------- symmetric 17-point DFT, in-place on strided LDS segment ----------
// X[k] = sum_n x[n] w^{kn}, w = exp(DIR*2*pi*i/17). Twiddles are compile-time
// float literals (SGPR-resident); sign handling via fma input modifiers.
template<int DIR>
__device__ __forceinline__ void dft17(float* __restrict__ re, float* __restrict__ im,
                                      int base, int stride)
{
    constexpr float C17[9] = {1.f, 0.93247223f, 0.73900892f, 0.44573836f,
                              0.09226836f, -0.27366299f, -0.60263464f,
                              -0.85021714f, -0.98297310f};
    constexpr float S17[9] = {0.f, 0.36124167f, 0.67369564f, 0.89516329f,
                              0.99573418f, 0.96182564f, 0.79801723f,
                              0.52643216f, 0.18374952f};
    constexpr float d = (DIR > 0) ? 1.f : -1.f;
    float xr[17], xi[17];
#pragma unroll
    for (int n = 0; n < 17; n++) { xr[n] = re[base + n*stride]; xi[n] = im[base + n*stride]; }
    float ar[8], ai[8], br[8], bi[8];
#pragma unroll
    for (int n = 1; n <= 8; n++) {
        ar[n-1] = xr[n] + xr[17-n];  ai[n-1] = xi[n] + xi[17-n];
        br[n-1] = xr[n] - xr[17-n];  bi[n-1] = xi[n] - xi[17-n];
    }
    float s0r = xr[0], s0i = xi[0];
#pragma unroll
    for (int n = 0; n < 8; n++) { s0r += ar[n]; s0i += ai[n]; }
    re[base] = s0r; im[base] = s0i;
#pragma unroll
    for (int k = 1; k <= 8; k++) {
        float Pr = xr[0], Pi = xi[0], Qr = 0.f, Qi = 0.f;
#pragma unroll
        for (int n = 1; n <= 8; n++) {
            int m = (k*n) % 17;                      // compile-time constant
            float cc = (m <= 8) ? C17[m] : C17[17-m];
            float ss = (m <= 8) ? S17[m] : -S17[17-m];
            Pr = fmaf(ar[n-1], cc, Pr);
            Pi = fmaf(ai[n-1], cc, Pi);
            Qr = fmaf(br[n-1], ss, Qr);
            Qi = fmaf(bi[n-1], ss, Qi);
        }
        re[base + k*stride]        = Pr - d*Qi;
        im[base + k*stride]        = Pi + d*Qr;
        re[base + (17-k)*stride]   = Pr + d*Qi;
        im[base + (17-k)*stride]   = Pi - d*Qr;
    }
}

// ---------- 136-point CT (8x17) along COLUMNS (positions stride RS) ----------
// Transforms `ncols` independent columns c: X[k1+8k2] lands at row-slot 17k1+k2.
// lut[t] = exp(DIR*2*pi*i*t/136).
template<int DIR>
__device__ void fft136_cols(float* __restrict__ re, float* __restrict__ im,
                            const float* __restrict__ lutc, const float* __restrict__ luts,
                            int ncols, int tid, int nth)
{
    constexpr float d = (DIR > 0) ? 1.0f : -1.0f;
    constexpr float C707 = 0.70710678118654752f;
    // Stage 1: radix-8 butterfly + folded twiddle w^k1, w = lut[n2].
    for (int e = tid; e < ncols*17; e += nth) {
        int c  = e / 17;
        int n2 = e - c*17;
        float xr[8], xi[8];
#pragma unroll
        for (int n1 = 0; n1 < 8; n1++) {
            int a = (17*n1 + n2)*RS + c;
            xr[n1] = re[a]; xi[n1] = im[a];
        }
        float e0r = xr[0]+xr[4], e0i = xi[0]+xi[4];
        float e1r = xr[0]-xr[4], e1i = xi[0]-xi[4];
        float o0r = xr[2]+xr[6], o0i = xi[2]+xi[6];
        float o1r = xr[2]-xr[6], o1i = xi[2]-xi[6];
        float E0r = e0r+o0r, E0i = e0i+o0i;
        float E2r = e0r-o0r, E2i = e0i-o0i;
        float E1r = e1r - d*o1i, E1i = e1i + d*o1r;
        float E3r = e1r + d*o1i, E3i = e1i - d*o1r;
        float f0r = xr[1]+xr[5], f0i = xi[1]+xi[5];
        float f1r = xr[1]-xr[5], f1i = xi[1]-xi[5];
        float h0r = xr[3]+xr[7], h0i = xi[3]+xi[7];
        float h1r = xr[3]-xr[7], h1i = xi[3]-xi[7];
        float O0r = f0r+h0r, O0i = f0i+h0i;
        float O2r = f0r-h0r, O2i = f0i-h0i;
        float O1r = f1r - d*h1i, O1i = f1i + d*h1r;
        float O3r = f1r + d*h1i, O3i = f1i - d*h1r;
        float t1r =  C707*(O1r - d*O1i), t1i = C707*(O1i + d*O1r);
        float t2r = -d*O2i,              t2i = d*O2r;
        float t3r = -C707*(O3r + d*O3i), t3i = C707*(d*O3r - O3i);
        float Xr[8], Xi[8];
        Xr[0]=E0r+O0r; Xi[0]=E0i+O0i;  Xr[4]=E0r-O0r; Xi[4]=E0i-O0i;
        Xr[1]=E1r+t1r; Xi[1]=E1i+t1i;  Xr[5]=E1r-t1r; Xi[5]=E1i-t1i;
        Xr[2]=E2r+t2r; Xi[2]=E2i+t2i;  Xr[6]=E2r-t2r; Xi[6]=E2i-t2i;
        Xr[3]=E3r+t3r; Xi[3]=E3i+t3i;  Xr[7]=E3r-t3r; Xi[7]=E3i-t3i;
        float wr = lutc[n2], wi = luts[n2];
        float cr = 1.f, ci = 0.f;
#pragma unroll
        for (int k1 = 0; k1 < 8; k1++) {
            int a = (17*k1 + n2)*RS + c;
            re[a] = Xr[k1]*cr - Xi[k1]*ci;
            im[a] = Xr[k1]*ci + Xi[k1]*cr;
            float ncr = cr*wr - ci*wi;
            ci = cr*wi + ci*wr; cr = ncr;
        }
    }
    __syncthreads();
    // Stage 2: symmetric 17-point DFT; freq k1+8k2 at slot 17k1+k2.
    for (int e = tid; e < ncols*8; e += nth) {
        int c  = e >> 3;
        int k1 = e & 7;
        dft17<DIR>(re, im, 17*k1*RS + c, RS);
    }
    __syncthreads();
}

// ---------- 68-point CT (4x17) along ROWS (positions stride 1) ----------
// All 136 rows; input natural cols 0..67, output X[k1+4k2] at col-slot 17k1+k2.
template<int DIR>
__device__ void ct68_rows(float* __restrict__ re, float* __restrict__ im,
                          const float* __restrict__ lutc, const float* __restrict__ luts,
                          int tid, int nth)
{
    constexpr float d = (DIR > 0) ? 1.0f : -1.0f;
    // Stage 1: radix-4 + folded twiddle w68^(k1*n2) = lut[2*n2]^k1.
    for (int e = tid; e < MDIM*17; e += nth) {
        int row = e / 17;
        int n2  = e - row*17;
        int base = row*RS;
        float xr[4], xi[4];
#pragma unroll
        for (int n1 = 0; n1 < 4; n1++) {
            xr[n1] = re[base + 17*n1 + n2];
            xi[n1] = im[base + 17*n1 + n2];
        }
        float t0r = xr[0]+xr[2], t0i = xi[0]+xi[2];
        float t1r = xr[0]-xr[2], t1i = xi[0]-xi[2];
        float t2r = xr[1]+xr[3], t2i = xi[1]+xi[3];
        float t3r = xr[1]-xr[3], t3i = xi[1]-xi[3];
        float Xr[4], Xi[4];
        Xr[0] = t0r+t2r;      Xi[0] = t0i+t2i;
        Xr[2] = t0r-t2r;      Xi[2] = t0i-t2i;
        Xr[1] = t1r - d*t3i;  Xi[1] = t1i + d*t3r;
        Xr[3] = t1r + d*t3i;  Xi[3] = t1i - d*t3r;
        float wr = lutc[2*n2], wi = luts[2*n2];
        float cr = 1.f, ci = 0.f;
#pragma unroll
        for (int k1 = 0; k1 < 4; k1++) {
            int a = base + 17*k1 + n2;
            re[a] = Xr[k1]*cr - Xi[k1]*ci;
            im[a] = Xr[k1]*ci + Xi[k1]*cr;
            float ncr = cr*wr - ci*wi;
            ci = cr*wi + ci*wr; cr = ncr;
        }
    }
    __syncthreads();
    // Stage 2: symmetric 17-point DFT per (row, k1).
    for (int e = tid; e < MDIM*4; e += nth) {
        int row = e >> 2;
        int k1  = e & 3;
        dft17<DIR>(re, im, row*RS + 17*k1, 1);
    }
    __syncthreads();
}

// ---------- Forward: one WG per (n,c) plane (256 WGs), r2c half-spectrum ----------
__global__ __launch_bounds__(1024, 8) void fwd_kernel(const float* __restrict__ x,
                                                      float2* __restrict__ Xhat)
{
    extern __shared__ float smem[];
    float* re   = smem;
    float* im   = smem + MDIM*RS;
    float* lutc = smem + 2*MDIM*RS;
    float* luts = lutc + MDIM;
    const int tid = threadIdx.x, nth = blockDim.x;

    for (int t = tid; t < MDIM; t += nth) {
        double s, c; sincos(-2.0*PI_D*(double)t/136.0, &s, &c);
        lutc[t] = (float)c; luts[t] = (float)s;
    }
    const float* xp = x + (size_t)blockIdx.x * (128*128);
    // Load packed rows: z[i][n] = xp(i, 2n) + i*xp(i, 2n+1), wrap pad by 4.
    for (int e = tid; e < MDIM*68; e += nth) {
        int i = e / 68, n = e - i*68;
        int si = (i + 124) & 127;
        int j0 = (2*n + 124) & 127;                  // always even, pair never wraps
        const float2 v = *reinterpret_cast<const float2*>(xp + si*128 + j0);
        re[i*RS + n] = v.x;
        im[i*RS + n] = v.y;
    }
    __syncthreads();
    ct68_rows<-1>(re, im, lutc, luts, tid, nth);     // rows: Z[k] at col-slot68(k)
    // r2c unpack: X[k] = E + w136^k * O ; item k handles (k, 68-k), in-place at slots.
    for (int e = tid; e < MDIM*35; e += nth) {
        int row = e / 35, k = e - row*35;
        int base = row*RS;
        int sa = slot68(k);
        float Zar = re[base+sa], Zai = im[base+sa];
        float Zbr, Zbi; int sb;
        if (k == 0) { Zbr = Zar; Zbi = Zai; sb = 68; }  // Z[68] == Z[0]; X[68] -> col 68
        else { int kk = 68-k; sb = slot68(kk); Zbr = re[base+sb]; Zbi = im[base+sb]; }
        float wc = lutc[k], ws = luts[k];               // w136^k (DIR=-1 LUT)
        float Er = 0.5f*(Zar + Zbr), Ei = 0.5f*(Zai - Zbi);
        float Dr = 0.5f*(Zar - Zbr), Di = 0.5f*(Zai + Zbi);
        float Tr = wc*Dr - ws*Di, Ti = wc*Di + ws*Dr;   // w^k * D
        re[base+sa] = Er + Ti;  im[base+sa] = Ei - Tr;  // X[k] = E - i*(w^k D)
        float E2r = Er,  E2i = -Ei;                     // 0.5(Zb + conj Za)
        float D2r = -Dr, D2i = Di;                      // 0.5(Zb - conj Za)
        float w2c = -wc, w2s = ws;                      // w136^(68-k) = -conj(w^k)
        float T2r = w2c*D2r - w2s*D2i, T2i = w2c*D2i + w2s*D2r;
        re[base+sb] = E2r + T2i;  im[base+sb] = E2i - T2r;  // X[68-k]
    }
    __syncthreads();
    fft136_cols<-1>(re, im, lutc, luts, HC, tid, nth);  // 69 columns
    // Store Xhat[g1][g2]; column of g2: slot68(g2) (g2<68) or 68; row: slot136(g1).
    float2* outp = Xhat + (size_t)blockIdx.x * PLANE_HALF;
    for (int e = tid; e < PLANE_HALF; e += nth) {
        int g1 = e / HC, g2 = e - g1*HC;
        int cq = (g2 == 68) ? 68 : slot68(g2);
        int a = slot136(g1)*RS + cq;
        outp[e] = make_float2(re[a], im[a]);
    }
}

// ---------- Per-channel multiplier precompute (double, table-driven trig) ----------
__global__ void prep_kernel(const float* __restrict__ weight,
                            const float* __restrict__ bias,
                            float2* __restrict__ Abuf)
{
    __shared__ double tabc[272], tabs[272];   // exp(-2*pi*i*t/272)
    for (int t = threadIdx.x; t < 272; t += blockDim.x) {
        double s, c; sincos(-2.0*PI_D*(double)t/272.0, &s, &c);
        tabc[t] = c; tabs[t] = s;
    }
    __syncthreads();

    const int c     = blockIdx.x >> 3;
    const int chunk = blockIdx.x & 7;
    const float* wp = weight + c*25;
    double w[25];
#pragma unroll
    for (int i = 0; i < 25; i++) w[i] = (double)wp[i];
    const double r = 1.0/(1.0 + exp(9.0 - (double)bias[c])) + 1e-5;

    const int e_lo = chunk * 1173;           // 8*1173 == PLANE_HALF
    const int e_hi = e_lo + 1173;
    for (int e = e_lo + (int)threadIdx.x; e < e_hi; e += blockDim.x) {
        int g1 = e / HC, g2 = e - g1*HC;
        double c1 = tabc[g1], s1 = tabs[g1];
        double c2 = tabc[g2], s2 = tabs[g2];
        double e1r[5], e1i[5], e2r[5], e2i[5];
        e1r[2]=1.0; e1i[2]=0.0; e1r[3]=c1; e1i[3]=s1;
        e1r[4]=c1*c1-s1*s1; e1i[4]=2.0*c1*s1;
        e1r[1]=c1; e1i[1]=-s1; e1r[0]=e1r[4]; e1i[0]=-e1i[4];
        e2r[2]=1.0; e2i[2]=0.0; e2r[3]=c2; e2i[3]=s2;
        e2r[4]=c2*c2-s2*s2; e2i[4]=2.0*c2*s2;
        e2r[1]=c2; e2i[1]=-s2; e2r[0]=e2r[4]; e2i[0]=-e2i[4];

        double R0r[5],R0i[5],R1r[5],R1i[5];
#pragma unroll
        for (int a = 0; a < 5; a++) {
            double r0r=0,r0i=0,r1r=0,r1i=0;
#pragma unroll
            for (int b = 0; b < 5; b++) {
                double wv = w[a*5+b];
                double pr = wv*e2r[b], pi = wv*e2i[b];
                r0r += pr; r0i += pi;
                if (b & 1) { r1r -= pr; r1i -= pi; } else { r1r += pr; r1i += pi; }
            }
            R0r[a]=r0r; R0i[a]=r0i; R1r[a]=r1r; R1i[a]=r1i;
        }
        double FBr[2][2], FBi[2][2];
#pragma unroll
        for (int a1 = 0; a1 < 2; a1++)
#pragma unroll
            for (int b1 = 0; b1 < 2; b1++) {
                double fr=0, fi=0;
#pragma unroll
                for (int a = 0; a < 5; a++) {
                    double er = e1r[a], ei = e1i[a];
                    if (a1 && (a & 1)) { er = -er; ei = -ei; }
                    double Rr = b1 ? R1r[a] : R0r[a];
                    double Ri = b1 ? R1i[a] : R0i[a];
                    fr += er*Rr - ei*Ri;
                    fi += er*Ri + ei*Rr;
                }
                FBr[a1][b1]=fr; FBi[a1][b1]=fi;
            }
        double ur[2]={1.0+c1, 1.0-c1}, ui[2]={s1, -s1};
        double vr[2]={1.0+c2, 1.0-c2}, vi[2]={s2, -s2};
        double Br_[2][2], Bi_[2][2];
#pragma unroll
        for (int a1 = 0; a1 < 2; a1++)
#pragma unroll
            for (int b1 = 0; b1 < 2; b1++) {
                Br_[a1][b1] = ur[a1]*vr[b1] - ui[a1]*vi[b1];
                Bi_[a1][b1] = ur[a1]*vi[b1] + ui[a1]*vr[b1];
            }
        double invW=0, Qr=0, Qi=0;
#pragma unroll
        for (int a1 = 0; a1 < 2; a1++)
#pragma unroll
            for (int b1 = 0; b1 < 2; b1++) {
                invW += FBr[a1][b1]*FBr[a1][b1] + FBi[a1][b1]*FBi[a1][b1];
                Qr += FBr[a1][b1]*Br_[a1][b1] - FBi[a1][b1]*Bi_[a1][b1];
                Qi += FBr[a1][b1]*Bi_[a1][b1] + FBi[a1][b1]*Br_[a1][b1];
            }
        invW *= 0.25; Qr *= 0.25; Qi *= 0.25;
        double den = 1.0/(invW + r);
        double Sr = (1.0 - Qr)*den, Si = -Qi*den;
        double Mr[2][2], Mi[2][2];
#pragma unroll
        for (int a1 = 0; a1 < 2; a1++)
#pragma unroll
            for (int b1 = 0; b1 < 2; b1++) {
                Mr[a1][b1] = Br_[a1][b1] + FBr[a1][b1]*Sr + FBi[a1][b1]*Si;
                Mi[a1][b1] = Bi_[a1][b1] + FBr[a1][b1]*Si - FBi[a1][b1]*Sr;
            }
        const double scale = 1.0/73984.0;   // 1/272^2 ifft normalization
#pragma unroll
        for (int uu = 0; uu < 2; uu++)
#pragma unroll
            for (int vv = 0; vv < 2; vv++) {
                double sr=0, si=0;
#pragma unroll
                for (int a1 = 0; a1 < 2; a1++)
#pragma unroll
                    for (int b1 = 0; b1 < 2; b1++) {
                        if ((a1*uu + b1*vv) & 1) { sr -= Mr[a1][b1]; si -= Mi[a1][b1]; }
                        else                     { sr += Mr[a1][b1]; si += Mi[a1][b1]; }
                    }
                int t = g1*uu + g2*vv;                 // <= 203 < 272
                double pc = tabc[t], ps = -tabs[t];    // exp(+i*pi*t/136)
                float2 outv;
                outv.x = (float)((pc*sr - ps*si)*scale);
                outv.y = (float)((pc*si + ps*sr)*scale);
                Abuf[((size_t)(c*4 + uu*2 + vv))*PLANE_HALF + e] = outv;
            }
    }
}

// ---------- Inverse: one WG per (n,c,u,v) (1024 WGs), Hermitian half-spectrum ----------
// blockIdx swizzle: v = bit 3 so the v-pair (same nc,u) is 8 apart -> same XCD
// (blockIdx%8 round-robin) -> their interleaved partial-line writes merge in L2.
__global__ __launch_bounds__(1024, 8) void inv_kernel(const float2* __restrict__ Xhat,
                                                      const float2* __restrict__ Abuf,
                                                      float* __restrict__ out)
{
    extern __shared__ float smem[];
    float* re   = smem;
    float* im   = smem + MDIM*RS;
    float* lutc = smem + 2*MDIM*RS;
    float* luts = lutc + MDIM;
    const int tid = threadIdx.x, nth = blockDim.x;

    for (int t = tid; t < MDIM; t += nth) {
        double s, c; sincos(2.0*PI_D*(double)t/136.0, &s, &c);   // inverse direction
        lutc[t] = (float)c; luts[t] = (float)s;
    }
    const int p  = blockIdx.x;        // 0..1023
    const int u  = p & 1;
    const int v  = (p >> 3) & 1;
    const int nc = ((p >> 4) << 2) | ((p >> 1) & 3);   // n*64 + c
    const int c  = nc & 63;
    const float2* Xp = Xhat + (size_t)nc * PLANE_HALF;
    const float2* Ap = Abuf + (size_t)(c*4 + u*2 + v) * PLANE_HALF;

    // Load S = A_uv * Xhat, natural [g1][g2], g2 = 0..68. (S is Hermitian.)
    for (int e = tid; e < PLANE_HALF; e += nth) {
        int g1 = e / HC, g2 = e - g1*HC;
        float2 xv = Xp[e], av = Ap[e];
        re[g1*RS + g2] = av.x*xv.x - av.y*xv.y;
        im[g1*RS + g2] = av.x*xv.y + av.y*xv.x;
    }
    __syncthreads();
    fft136_cols<1>(re, im, lutc, luts, HC, tid, nth);   // rows become slot136(y1)
    // c2r pack per row: Zf[k] = (T[k]+conj T[68-k]) + i*V^k*(T[k]-conj T[68-k]).
    for (int e = tid; e < MDIM*35; e += nth) {
        int row = e / 35, k = e - row*35;
        int base = row*RS;
        float Tar = re[base+k],    Tai = im[base+k];
        float Tbr = re[base+68-k], Tbi = im[base+68-k];
        float Sr = Tar + Tbr, Si = Tai - Tbi;
        float Dr = Tar - Tbr, Di = Tai + Tbi;
        float wc = lutc[k], ws = luts[k];               // V^k = exp(+2pi i k/136)
        float Or = wc*Dr - ws*Di, Oi = wc*Di + ws*Dr;
        re[base+k] = Sr - Oi;                           // Zf[k] = S + i*O
        im[base+k] = Si + Or;
        if (k >= 1 && k <= 33) {                        // Zf[68-k]
            float S2r = Tbr + Tar, S2i = Tbi - Tai;
            float D2r = Tbr - Tar, D2i = Tbi + Tai;
            float w2c = -wc, w2s = ws;                  // V^(68-k) = -conj(V^k)
            float O2r = w2c*D2r - w2s*D2i, O2i = w2c*D2i + w2s*D2r;
            re[base+68-k] = S2r - O2i;
            im[base+68-k] = S2i + O2r;
        }
    }
    __syncthreads();
    ct68_rows<1>(re, im, lutc, luts, tid, nth);         // w[m] at col-slot68(m)
    // Store: row y1 at physical slot136(y1); re -> col 4m+v-8, im -> col 4m+v-6.
    float* op = out + (size_t)nc * (256*256);
    for (int e = tid; e < 128*64; e += nth) {
        int y1 = 4 + (e >> 6);            // [4,132)
        int m  = 2 + (e & 63);            // [2,66)
        int a  = slot136(y1)*RS + slot68(m);
        int o1 = 2*y1 + u - 8;
        float wr = re[a], wi = im[a];
        op[o1*256 + 4*m + v - 8] = wr;    // y2' = 2m   (even within parity grid)
        op[o1*256 + 4*m + v - 6] = wi;    // y2' = 2m+1
    }
}

extern "C" void kernel_launch(void* const* d_in, const int* in_sizes, int n_in,
                              void* d_out, int out_size, void* d_ws, size_t ws_size,
                              hipStream_t stream)
{
    const float* x      = (const float*)d_in[0];
    const float* weight = (const float*)d_in[1];
    const float* bias   = (const float*)d_in[2];
    float* out = (float*)d_out;

    float2* Xhat = (float2*)d_ws;                       // 256 * 9384 * 8B = 19.2 MB
    float2* Abuf = Xhat + (size_t)NPLANES * PLANE_HALF; // 256 * 9384 * 8B = 19.2 MB

    const size_t lds_bytes = (size_t)LDS_FLOATS * sizeof(float);  // 77,248 B
    (void)hipFuncSetAttribute((const void*)fwd_kernel,
                              hipFuncAttributeMaxDynamicSharedMemorySize, (int)lds_bytes);
    (void)hipFuncSetAttribute((const void*)inv_kernel,
                              hipFuncAttributeMaxDynamicSharedMemorySize, (int)lds_bytes);

    prep_kernel<<<512, 256, 0, stream>>>(weight, bias, Abuf);
    fwd_kernel<<<NPLANES, 1024, lds_bytes, stream>>>(x, Xhat);
    inv_kernel<<<NPLANES*4, 1024, lds_bytes, stream>>>(Xhat, Abuf, out);
}